// Round 3
// baseline (164.213 us; speedup 1.0000x reference)
//
#include <hip/hip_runtime.h>
#include <hip/hip_bf16.h>
#include <math.h>

// Problem constants (B,F,H,E,O) = (512,512,512,8,512)
enum { Bq = 512, Fq = 512, Hq = 512, Eq = 8, Oq = 512 };

typedef __attribute__((ext_vector_type(8))) short short8;
typedef __attribute__((ext_vector_type(4))) float floatx4;

static __device__ __forceinline__ unsigned short f2bf(float f) {
  unsigned u = __float_as_uint(f);
  u += 0x7fffu + ((u >> 16) & 1u);
  return (unsigned short)(u >> 16);
}
static __device__ __forceinline__ float bf2f(unsigned short h) {
  return __uint_as_float(((unsigned)h) << 16);
}
static __device__ __forceinline__ float elu1(float v) {
  return v > 0.f ? v : (__expf(v) - 1.f);
}

// async global->LDS 16B copy (wave-uniform LDS base + lane*16 scatter)
typedef __attribute__((address_space(1))) const unsigned int gu32;
typedef __attribute__((address_space(3))) unsigned int lu32;
static __device__ __forceinline__ void gld16(const unsigned short* g,
                                             unsigned short* l) {
  __builtin_amdgcn_global_load_lds((gu32*)g, (lu32*)l, 16, 0, 0);
}

// ---------- fp32 -> bf16 convert, 3 big (alpha) + 3 small segments ----------
__global__ __launch_bounds__(256) void cvt6_kernel(
    const float* __restrict__ b0, const float* __restrict__ b1,
    const float* __restrict__ b2, unsigned short* __restrict__ db0,
    unsigned short* __restrict__ db1, unsigned short* __restrict__ db2,
    const float* __restrict__ s0, const float* __restrict__ s1,
    const float* __restrict__ s2, unsigned short* __restrict__ ds0,
    unsigned short* __restrict__ ds1, unsigned short* __restrict__ ds2,
    int nb, int ns) {
  int i = blockIdx.x * 256 + threadIdx.x;
  const float4* s;
  unsigned short* d;
  int j;
  if (i < 3 * nb) {
    int seg = i / nb;
    j = i - seg * nb;
    s = (seg == 0) ? (const float4*)b0
      : (seg == 1) ? (const float4*)b1 : (const float4*)b2;
    d = (seg == 0) ? db0 : (seg == 1) ? db1 : db2;
  } else {
    int k = i - 3 * nb;
    if (k >= 3 * ns) return;
    int seg = k / ns;
    j = k - seg * ns;
    s = (seg == 0) ? (const float4*)s0
      : (seg == 1) ? (const float4*)s1 : (const float4*)s2;
    d = (seg == 0) ? ds0 : (seg == 1) ? ds1 : ds2;
  }
  float4 v = s[j];
  ushort4 o;
  o.x = f2bf(v.x); o.y = f2bf(v.y); o.z = f2bf(v.z); o.w = f2bf(v.w);
  *(ushort4*)(d + 4 * (size_t)j) = o;
}

// ------------- gating GEMM: C[M,N] = elu(A[M,K] @ W[N,K]^T + b) -------------
template <int BM, int BN, int BK, int TM, int TN>
__global__ __launch_bounds__(256) void gemm_bt(
    const unsigned short* __restrict__ A, const unsigned short* __restrict__ W,
    const float* __restrict__ bias, unsigned short* __restrict__ Cb,
    int M, int N, int K) {
  __shared__ unsigned short As[BM * BK];
  __shared__ unsigned short Bs[BN * BK];
  const int tid = threadIdx.x;
  const int wave = tid >> 6, lane = tid & 63;
  const int wm = wave >> 1, wn = wave & 1;
  const int lr = lane & 15, lk = lane >> 4;
  const int m0 = blockIdx.y * BM, n0 = blockIdx.x * BN;
  constexpr int WMt = BM / 2, WNt = BN / 2;
  constexpr int CPR = BK / 8;
  constexpr int CHA = BM * CPR, CHB = BN * CPR;

  floatx4 acc[TM][TN];
#pragma unroll
  for (int i = 0; i < TM; i++)
#pragma unroll
    for (int j = 0; j < TN; j++) acc[i][j] = (floatx4){0.f, 0.f, 0.f, 0.f};

  for (int k0 = 0; k0 < K; k0 += BK) {
#pragma unroll
    for (int c = tid; c < CHA; c += 256) {
      int r = c / CPR, q = c % CPR;
      gld16(&A[(size_t)(m0 + r) * K + k0 + q * 8], &As[(c & ~63) * 8]);
    }
#pragma unroll
    for (int c = tid; c < CHB; c += 256) {
      int r = c / CPR, q = c % CPR;
      gld16(&W[(size_t)(n0 + r) * K + k0 + q * 8], &Bs[(c & ~63) * 8]);
    }
    __syncthreads();
#pragma unroll
    for (int kk = 0; kk < BK; kk += 32) {
      short8 af[TM], bw[TN];
#pragma unroll
      for (int i = 0; i < TM; i++)
        af[i] = *(const short8*)&As[(wm * WMt + i * 16 + lr) * BK + kk + lk * 8];
#pragma unroll
      for (int j = 0; j < TN; j++)
        bw[j] = *(const short8*)&Bs[(wn * WNt + j * 16 + lr) * BK + kk + lk * 8];
#pragma unroll
      for (int i = 0; i < TM; i++)
#pragma unroll
        for (int j = 0; j < TN; j++)
          acc[i][j] = __builtin_amdgcn_mfma_f32_16x16x32_bf16(
              af[i], bw[j], acc[i][j], 0, 0, 0);
    }
    __syncthreads();
  }

  // C/D layout (m89-verified): col = lane&15, row = (lane>>4)*4 + reg
#pragma unroll
  for (int i = 0; i < TM; i++) {
#pragma unroll
    for (int j = 0; j < TN; j++) {
#pragma unroll
      for (int r = 0; r < 4; r++) {
        int m = m0 + wm * WMt + i * 16 + lk * 4 + r;
        int n = n0 + wn * WNt + j * 16 + lr;
        float v = acc[i][j][r] + bias[n];
        Cb[(size_t)m * N + n] = f2bf(elu1(v));
      }
    }
  }
}

// -------- fused expert GEMM: P[z][b][h] = g[b,e] * (act @ alpha_e^T) --------
// grid (Hq/BN, Bq/BM, Eq*2): z -> e = z>>1, ks = z&1 (split-K halves).
template <int BM, int BN, int BK, int TM, int TN>
__global__ __launch_bounds__(256) void expert_gemm(
    const unsigned short* __restrict__ A,   // [B, 512] bf16 activations
    const unsigned short* __restrict__ Wb,  // [E*512, 512] bf16 alpha bank
    const float* __restrict__ g,            // [B, E] gates
    float* __restrict__ P) {                // [16][B][512] partials
  __shared__ unsigned short As[BM * BK];
  __shared__ unsigned short Bs[BN * BK];
  const int tid = threadIdx.x;
  const int wave = tid >> 6, lane = tid & 63;
  const int wm = wave >> 1, wn = wave & 1;
  const int lr = lane & 15, lk = lane >> 4;
  const int m0 = blockIdx.y * BM, n0 = blockIdx.x * BN;
  const int e = blockIdx.z >> 1, ks = blockIdx.z & 1;
  const int kbeg = ks * 256, kend = kbeg + 256;
  const unsigned short* W = Wb + (size_t)e * Hq * 512 + (size_t)n0 * 512;
  constexpr int WMt = BM / 2, WNt = BN / 2;
  constexpr int CPR = BK / 8;
  constexpr int CHA = BM * CPR, CHB = BN * CPR;

  floatx4 acc[TM][TN];
#pragma unroll
  for (int i = 0; i < TM; i++)
#pragma unroll
    for (int j = 0; j < TN; j++) acc[i][j] = (floatx4){0.f, 0.f, 0.f, 0.f};

  for (int k0 = kbeg; k0 < kend; k0 += BK) {
#pragma unroll
    for (int c = tid; c < CHA; c += 256) {
      int r = c / CPR, q = c % CPR;
      gld16(&A[(size_t)(m0 + r) * 512 + k0 + q * 8], &As[(c & ~63) * 8]);
    }
#pragma unroll
    for (int c = tid; c < CHB; c += 256) {
      int r = c / CPR, q = c % CPR;
      gld16(&W[(size_t)r * 512 + k0 + q * 8], &Bs[(c & ~63) * 8]);
    }
    __syncthreads();
#pragma unroll
    for (int kk = 0; kk < BK; kk += 32) {
      short8 af[TM], bw[TN];
#pragma unroll
      for (int i = 0; i < TM; i++)
        af[i] = *(const short8*)&As[(wm * WMt + i * 16 + lr) * BK + kk + lk * 8];
#pragma unroll
      for (int j = 0; j < TN; j++)
        bw[j] = *(const short8*)&Bs[(wn * WNt + j * 16 + lr) * BK + kk + lk * 8];
#pragma unroll
      for (int i = 0; i < TM; i++)
#pragma unroll
        for (int j = 0; j < TN; j++)
          acc[i][j] = __builtin_amdgcn_mfma_f32_16x16x32_bf16(
              af[i], bw[j], acc[i][j], 0, 0, 0);
    }
    __syncthreads();
  }

  float* Po = P + (size_t)blockIdx.z * Bq * Hq;
#pragma unroll
  for (int i = 0; i < TM; i++) {
#pragma unroll
    for (int j = 0; j < TN; j++) {
#pragma unroll
      for (int r = 0; r < 4; r++) {
        int m = m0 + wm * WMt + i * 16 + lk * 4 + r;
        int n = n0 + wn * WNt + j * 16 + lr;
        Po[(size_t)m * Hq + n] = acc[i][j][r] * g[m * Eq + e];
      }
    }
  }
}

// ---------------- gate logits + softmax (one wave per sample) ----------------
__global__ __launch_bounds__(64) void gate_kernel(
    const unsigned short* __restrict__ G1,  // [B,H] bf16
    const float* __restrict__ gw2,          // [E,H]
    const float* __restrict__ gb2,          // [E]
    float* __restrict__ g) {                // [B,E]
  int b = blockIdx.x;
  int lane = threadIdx.x;
  float xv[8];
#pragma unroll
  for (int t = 0; t < 8; t++) xv[t] = bf2f(G1[(size_t)b * Hq + t * 64 + lane]);
  float le[Eq];
#pragma unroll
  for (int e = 0; e < Eq; e++) {
    float p = 0.f;
#pragma unroll
    for (int t = 0; t < 8; t++)
      p += xv[t] * gw2[(size_t)e * Hq + t * 64 + lane];
#pragma unroll
    for (int o = 32; o > 0; o >>= 1) p += __shfl_xor(p, o);
    le[e] = p + gb2[e];
  }
  float m = le[0];
#pragma unroll
  for (int e = 1; e < Eq; e++) m = fmaxf(m, le[e]);
  float s = 0.f;
#pragma unroll
  for (int e = 0; e < Eq; e++) {
    le[e] = __expf(le[e] - m);
    s += le[e];
  }
  float inv = 1.f / s;
  if (lane == 0) {
#pragma unroll
    for (int e = 0; e < Eq; e++) g[(size_t)b * Eq + e] = le[e] * inv;
  }
}

// ----- slice reduce: out = sum_z P[z] + sum_e g[b,e]*beta[e]  (+opt ELU) -----
template <int ACT>
__global__ __launch_bounds__(256) void reduce_kernel(
    const float* __restrict__ P,     // [16][B][H]
    const float* __restrict__ g,     // [B, E]
    const float* __restrict__ beta,  // [E*H]
    unsigned short* __restrict__ outb, float* __restrict__ outf) {
  int idx = blockIdx.x * 256 + threadIdx.x;  // over B*H/4
  int b = idx >> 7, h4 = (idx & 127) << 2;
  float4 s = {0.f, 0.f, 0.f, 0.f};
#pragma unroll
  for (int z = 0; z < 16; z++) {
    float4 v = *(const float4*)&P[((size_t)z * Bq + b) * Hq + h4];
    s.x += v.x; s.y += v.y; s.z += v.z; s.w += v.w;
  }
  const float* gb = g + (size_t)b * Eq;
#pragma unroll
  for (int e = 0; e < Eq; e++) {
    float ge = gb[e];
    float4 bv = *(const float4*)&beta[e * Hq + h4];
    s.x += ge * bv.x; s.y += ge * bv.y; s.z += ge * bv.z; s.w += ge * bv.w;
  }
  if (ACT) {
    ushort4 o;
    o.x = f2bf(elu1(s.x)); o.y = f2bf(elu1(s.y));
    o.z = f2bf(elu1(s.z)); o.w = f2bf(elu1(s.w));
    *(ushort4*)&outb[(size_t)idx * 4] = o;
  } else {
    *(float4*)&outf[(size_t)idx * 4] = s;
  }
}

extern "C" void kernel_launch(void* const* d_in, const int* in_sizes, int n_in,
                              void* d_out, int out_size, void* d_ws,
                              size_t ws_size, hipStream_t stream) {
  const float* x = (const float*)d_in[0];
  const float* gw0 = (const float*)d_in[1];
  const float* gb0 = (const float*)d_in[2];
  const float* gw1 = (const float*)d_in[3];
  const float* gb1 = (const float*)d_in[4];
  const float* gw2 = (const float*)d_in[5];
  const float* gb2 = (const float*)d_in[6];
  const float* alpha0 = (const float*)d_in[7];
  const float* beta0 = (const float*)d_in[8];
  const float* alpha1 = (const float*)d_in[9];
  const float* beta1 = (const float*)d_in[10];
  const float* alpha2 = (const float*)d_in[11];
  const float* beta2 = (const float*)d_in[12];
  float* out = (float*)d_out;

  char* ws = (char*)d_ws;
  auto alloc = [&](size_t bytes) {
    char* p = ws;
    ws += (bytes + 255) & ~(size_t)255;
    return p;
  };
  unsigned short* xb = (unsigned short*)alloc((size_t)Bq * Fq * 2);
  unsigned short* gw0b = (unsigned short*)alloc((size_t)Hq * Fq * 2);
  unsigned short* gw1b = (unsigned short*)alloc((size_t)Hq * Hq * 2);
  unsigned short* a0b = (unsigned short*)alloc((size_t)Eq * Hq * Fq * 2);
  unsigned short* a1b = (unsigned short*)alloc((size_t)Eq * Hq * Hq * 2);
  unsigned short* a2b = (unsigned short*)alloc((size_t)Eq * Oq * Hq * 2);
  unsigned short* G0b = (unsigned short*)alloc((size_t)Bq * Hq * 2);
  unsigned short* G1b = (unsigned short*)alloc((size_t)Bq * Hq * 2);
  unsigned short* H1b = (unsigned short*)alloc((size_t)Bq * Hq * 2);
  unsigned short* H2b = (unsigned short*)alloc((size_t)Bq * Hq * 2);
  float* gates = (float*)alloc((size_t)Bq * Eq * 4);
  float* P = (float*)alloc((size_t)16 * Bq * Hq * 4);  // gate-scaled partials

  // 1) all fp32->bf16 converts in one launch
  {
    int nb = (Eq * Hq * Fq) / 4, ns = (Bq * Fq) / 4;
    int total = 3 * nb + 3 * ns;
    cvt6_kernel<<<(total + 255) / 256, 256, 0, stream>>>(
        alpha0, alpha1, alpha2, a0b, a1b, a2b, x, gw0, gw1, xb, gw0b, gw1b,
        nb, ns);
  }

  // 2) gating MLP: 32x64 tiles -> 128 blocks each
  dim3 gg(Hq / 64, Bq / 32);
  gemm_bt<32, 64, 64, 1, 2><<<gg, 256, 0, stream>>>(xb, gw0b, gb0, G0b,
                                                    Bq, Hq, Fq);
  gemm_bt<32, 64, 64, 1, 2><<<gg, 256, 0, stream>>>(G0b, gw1b, gb1, G1b,
                                                    Bq, Hq, Hq);

  // 3) gate logits + softmax
  gate_kernel<<<Bq, 64, 0, stream>>>(G1b, gw2, gb2, gates);

  // 4) experts: gate-scaled GEMM partials (512 blocks) + thin slice-reduce
  dim3 ge(Hq / 128, Bq / 64, Eq * 2);
  dim3 gr((Bq * Hq / 4) / 256);
  expert_gemm<64, 128, 64, 2, 4><<<ge, 256, 0, stream>>>(xb, a0b, gates, P);
  reduce_kernel<1><<<gr, 256, 0, stream>>>(P, gates, beta0, H1b, nullptr);
  expert_gemm<64, 128, 64, 2, 4><<<ge, 256, 0, stream>>>(H1b, a1b, gates, P);
  reduce_kernel<1><<<gr, 256, 0, stream>>>(P, gates, beta1, H2b, nullptr);
  expert_gemm<64, 128, 64, 2, 4><<<ge, 256, 0, stream>>>(H2b, a2b, gates, P);
  reduce_kernel<0><<<gr, 256, 0, stream>>>(P, gates, beta2, nullptr, out);
}